// Round 10
// baseline (1331.204 us; speedup 1.0000x reference)
//
#include <hip/hip_runtime.h>
#include <stdint.h>

#define KSPLIT 8

__device__ __forceinline__ uint32_t pack4f(float4 f) {
  int x = (int)f.x, y = (int)f.y, z = (int)f.z, w = (int)f.w;
  x = min(max(x, 0), 255); y = min(max(y, 0), 255);
  z = min(max(z, 0), 255); w = min(max(w, 0), 255);
  return (uint32_t)x | ((uint32_t)y << 8) | ((uint32_t)z << 16) | ((uint32_t)w << 24);
}

// clip + swizzle code w -> w' = (w>>2) | ((w&3)<<6)  (T-table gather index)
__device__ __forceinline__ uint32_t pack4f_swz(float4 f) {
  float vv[4] = {f.x, f.y, f.z, f.w};
  uint32_t r = 0;
#pragma unroll
  for (int i = 0; i < 4; i++) {
    uint32_t w = (uint32_t)min(max((int)vv[i], 0), 255);
    w = (w >> 2) | ((w & 3u) << 6);
    r |= w << (8 * i);
  }
  return r;
}

__device__ __forceinline__ uint32_t qword(const uint4& v, int q) {
  return q == 0 ? v.x : q == 1 ? v.y : q == 2 ? v.z : v.w;
}

// 256x256 int32 LUT -> u8 linear
__global__ __launch_bounds__(256) void pack_lut_k(const int* __restrict__ lut,
                                                  uint8_t* __restrict__ out, int n16) {
  int t = blockIdx.x * 256 + threadIdx.x;
  if (t >= n16) return;
  const int4* s = (const int4*)lut;
  uint32_t w[4];
#pragma unroll
  for (int q = 0; q < 4; q++) {
    int4 v = s[t * 4 + q];
    w[q] = (uint32_t)(v.x & 255) | ((uint32_t)(v.y & 255) << 8) |
           ((uint32_t)(v.z & 255) << 16) | ((uint32_t)(v.w & 255) << 24);
  }
  ((uint4*)out)[t] = make_uint4(w[0], w[1], w[2], w[3]);
}

// input [M][K] f32 codes -> u8 codes, same layout
__global__ __launch_bounds__(256) void pack_lin_k(const float* __restrict__ a,
                                                  uint8_t* __restrict__ out, int n16) {
  int t = blockIdx.x * 256 + threadIdx.x;
  if (t >= n16) return;
  const float4* s = (const float4*)a;
  uint32_t w[4];
#pragma unroll
  for (int q = 0; q < 4; q++) w[q] = pack4f(s[t * 4 + q]);
  ((uint4*)out)[t] = make_uint4(w[0], w[1], w[2], w[3]);
}

// weight [N][K] f32 -> chunk-transposed [K/16][N][16] u8 with SWIZZLED codes
__global__ __launch_bounds__(256) void pack_wt_swz_k(const float* __restrict__ w,
                                                     uint8_t* __restrict__ out, int N, int K) {
  int t = blockIdx.x * 256 + threadIdx.x;
  int cpk = K >> 4;
  if (t >= N * cpk) return;
  int n = t / cpk, c = t - n * cpk;
  const float4* s = (const float4*)(w + (size_t)n * K + (size_t)c * 16);
  uint32_t x0 = pack4f_swz(s[0]), x1 = pack4f_swz(s[1]), x2 = pack4f_swz(s[2]), x3 = pack4f_swz(s[3]);
  *(uint4*)(out + ((size_t)c * N + n) * 16) = make_uint4(x0, x1, x2, x3);
}

__global__ __launch_bounds__(256) void zero_k(uint32_t* __restrict__ p, int n4) {
  int i = blockIdx.x * 256 + threadIdx.x;
  if (i < n4) ((uint4*)p)[i] = make_uint4(0u, 0u, 0u, 0u);
}

__global__ __launch_bounds__(256) void finalize_k(uint32_t* __restrict__ io,
                                                  const float* __restrict__ bias,
                                                  int n4, int N) {
  int i = blockIdx.x * 256 + threadIdx.x;
  if (i >= n4) return;
  uint4 v = ((const uint4*)io)[i];
  int base = (i * 4) % N;
  float4 f;
  f.x = (float)v.x + bias[base + 0];
  f.y = (float)v.y + bias[base + 1];
  f.z = (float)v.z + bias[base + 2];
  f.w = (float)v.w + bias[base + 3];
  ((float4*)io)[i] = f;
}

// Main v3: 16-row waves, LUT rows read from L1/L2 (not LDS), LDS holds only
// per-wave T-tables (4KB each). Per kk: 16 coalesced 256B LUT-row loads ->
// perm transpose -> conflict-free ds_write_b128 -> per column ONE
// ds_read_b128 gather serves 16 row-updates (u16-pair SWAR accumulate).
__global__ __launch_bounds__(256, 4) void lutmm_ttab16(
    const uint8_t* __restrict__ A8,   // [M][K] u8 codes
    const uint8_t* __restrict__ WT,   // [K/16][N][16] u8, swizzled codes
    const uint8_t* __restrict__ LUT8, // [256][256] u8 linear
    uint32_t* __restrict__ out32,     // [M][N] u32, pre-zeroed
    int M, int N, int K) {
  __shared__ uint4 T4[4 * 256];       // 16KB total, 4KB per wave
  const int lane = threadIdx.x & 63;
  const int wid  = __builtin_amdgcn_readfirstlane((int)(threadIdx.x >> 6));
  const int rg = wid >> 1, cg = wid & 1;
  const int cbi = blockIdx.x / KSPLIT;
  const int ks  = blockIdx.x - cbi * KSPLIT;
  const int r0  = blockIdx.y * 32 + rg * 16;      // wave's 16 rows
  const int cb  = cbi * 1024 + cg * 512;          // wave's 512-col group
  const int k0  = ks * (K / KSPLIT);
  const int kend = k0 + K / KSPLIT;
  uint4* Tw = &T4[wid * 256];
  const int vcol4 = lane << 2;                    // byte offset in a LUT row

  uint32_t acc[8][8] = {};   // [col c][row-pair q]; u16 pairs, max 256*255 < 2^16

  for (int kc = k0; kc < kend; kc += 8) {
    uint2 aw[16];            // wave-uniform A codes (scalar loads)
#pragma unroll
    for (int j = 0; j < 16; j++)
      aw[j] = *(const uint2*)(A8 + (size_t)(r0 + j) * K + kc);
    uint2 wv[8];
    const uint8_t* wtb = WT + ((size_t)(kc >> 4) * N) * 16 + (kc & 15);
#pragma unroll
    for (int c = 0; c < 8; c++)
      wv[c] = *(const uint2*)(wtb + (size_t)(cb + c * 64 + lane) * 16);  // coalesced

#pragma unroll
    for (int kk = 0; kk < 8; kk++) {
      const int sh = (kk & 3) * 8;
      uint32_t r_[16];
#pragma unroll
      for (int j = 0; j < 16; j++) {
        uint32_t a = (((kk < 4) ? aw[j].x : aw[j].y) >> sh) & 255u;
        r_[j] = *(const uint32_t*)(LUT8 + (a << 8) + vcol4);  // 256B coalesced, L1/L2
      }
      // transpose: entry w = 4*lane+p gets bytes {row0..row15}[w]
#pragma unroll
      for (int p = 0; p < 4; p++) {
        uint32_t selp = (uint32_t)p | ((uint32_t)(4 + p) << 8) |
                        ((uint32_t)p << 16) | ((uint32_t)(4 + p) << 24);
        uint32_t u[4];
#pragma unroll
        for (int i = 0; i < 4; i++) {
          uint32_t tA = __builtin_amdgcn_perm(r_[4 * i + 1], r_[4 * i + 0], selp);
          uint32_t tB = __builtin_amdgcn_perm(r_[4 * i + 3], r_[4 * i + 2], selp);
          u[i] = __builtin_amdgcn_perm(tB, tA, 0x05040100u);
        }
        Tw[lane | (p << 6)] = make_uint4(u[0], u[1], u[2], u[3]);  // conflict-free b128
      }
      // gathers: one b128 per column serves 16 rows
#pragma unroll
      for (int c = 0; c < 8; c++) {
        uint32_t wq = (((kk < 4) ? wv[c].x : wv[c].y) >> sh) & 255u;  // pre-swizzled w'
        uint4 g = Tw[wq];
        acc[c][0] += __builtin_amdgcn_perm(0u, g.x, 0x05010400u);  // rows 0,1
        acc[c][1] += __builtin_amdgcn_perm(0u, g.x, 0x05030402u);  // rows 2,3
        acc[c][2] += __builtin_amdgcn_perm(0u, g.y, 0x05010400u);  // rows 4,5
        acc[c][3] += __builtin_amdgcn_perm(0u, g.y, 0x05030402u);  // rows 6,7
        acc[c][4] += __builtin_amdgcn_perm(0u, g.z, 0x05010400u);  // rows 8,9
        acc[c][5] += __builtin_amdgcn_perm(0u, g.z, 0x05030402u);  // rows 10,11
        acc[c][6] += __builtin_amdgcn_perm(0u, g.w, 0x05010400u);  // rows 12,13
        acc[c][7] += __builtin_amdgcn_perm(0u, g.w, 0x05030402u);  // rows 14,15
      }
    }
  }

#pragma unroll
  for (int c = 0; c < 8; c++) {
    int col = cb + c * 64 + lane;
#pragma unroll
    for (int q = 0; q < 8; q++) {
      uint32_t v = acc[c][q];
      atomicAdd(&out32[(size_t)(r0 + 2 * q) * N + col], v & 0xFFFFu);
      atomicAdd(&out32[(size_t)(r0 + 2 * q + 1) * N + col], v >> 16);
    }
  }
}

// Fallback: direct f32 reads (R1-proven structure).
__global__ __launch_bounds__(1024, 8) void lutmm_f32(
    const float* __restrict__ A, const float* __restrict__ W,
    const int* __restrict__ LUT32, const float* __restrict__ bias,
    float* __restrict__ out, int M, int N, int K) {
  __shared__ uint8_t lut[65536];
  for (int i = threadIdx.x; i < 16384; i += 1024) {
    int4 v = ((const int4*)LUT32)[i];
    ((uint32_t*)lut)[i] = (uint32_t)(v.x & 255) | ((uint32_t)(v.y & 255) << 8) |
                          ((uint32_t)(v.z & 255) << 16) | ((uint32_t)(v.w & 255) << 24);
  }
  __syncthreads();

  const int lane = threadIdx.x & 63;
  const int wid = threadIdx.x >> 6;
  const int r0 = blockIdx.y * 16 + wid;
  const int cbase = blockIdx.x * 256 + lane;
  uint32_t acc[4] = {};

  for (int kb = 0; kb < K; kb += 16) {
    const float4* sa = (const float4*)(A + (size_t)r0 * K + kb);
    uint4 ap = make_uint4(pack4f(sa[0]), pack4f(sa[1]), pack4f(sa[2]), pack4f(sa[3]));
    uint4 wp[4];
#pragma unroll
    for (int j = 0; j < 4; j++) {
      const float4* s = (const float4*)(W + (size_t)(cbase + j * 64) * K + kb);
      wp[j] = make_uint4(pack4f(s[0]), pack4f(s[1]), pack4f(s[2]), pack4f(s[3]));
    }
#pragma unroll
    for (int q = 0; q < 4; q++)
#pragma unroll
      for (int b = 0; b < 4; b++) {
        uint32_t as = ((qword(ap, q) >> (b * 8)) & 255u) << 8;
#pragma unroll
        for (int j = 0; j < 4; j++)
          acc[j] += lut[as | ((qword(wp[j], q) >> (b * 8)) & 255u)];
      }
  }

#pragma unroll
  for (int j = 0; j < 4; j++) {
    int c = cbase + j * 64;
    out[(size_t)r0 * N + c] = (float)acc[j] + bias[c];
  }
}

extern "C" void kernel_launch(void* const* d_in, const int* in_sizes, int n_in,
                              void* d_out, int out_size, void* d_ws, size_t ws_size,
                              hipStream_t stream) {
  const float* inp  = (const float*)d_in[0];  // [M][K]
  const float* wgt  = (const float*)d_in[1];  // [N][K]
  const float* bias = (const float*)d_in[2];  // [N]
  const int*   lut  = (const int*)d_in[3];    // [256][256]

  const int N = in_sizes[2];
  const int K = in_sizes[1] / N;
  const int M = in_sizes[0] / K;

  size_t need = 65536 + (size_t)M * K + (size_t)N * K;

  if (ws_size >= need && (N % 1024) == 0 && (M % 32) == 0 &&
      (K % (KSPLIT * 16)) == 0 && (K / KSPLIT) <= 256) {
    uint8_t* lut8 = (uint8_t*)d_ws;
    uint8_t* a8   = lut8 + 65536;           // [M][K]
    uint8_t* wt8  = a8 + (size_t)M * K;     // [K/16][N][16], swizzled codes
    pack_lut_k<<<16, 256, 0, stream>>>(lut, lut8, 65536 / 16);
    int an16 = (M * K) / 16;
    pack_lin_k<<<(an16 + 255) / 256, 256, 0, stream>>>(inp, a8, an16);
    int wn16 = (N * K) / 16;
    pack_wt_swz_k<<<(wn16 + 255) / 256, 256, 0, stream>>>(wgt, wt8, N, K);

    uint32_t* out32 = (uint32_t*)d_out;
    int n4 = (M * N) / 4;
    zero_k<<<(n4 + 255) / 256, 256, 0, stream>>>(out32, n4);
    dim3 grid((N / 1024) * KSPLIT, M / 32);
    lutmm_ttab16<<<grid, 256, 0, stream>>>(a8, wt8, lut8, out32, M, N, K);
    finalize_k<<<(n4 + 255) / 256, 256, 0, stream>>>(out32, bias, n4, N);
  } else {
    dim3 grid(N / 256, M / 16);
    lutmm_f32<<<grid, 1024, 0, stream>>>(inp, wgt, lut, bias, (float*)d_out, M, N, K);
  }
}